// Round 5
// baseline (20501.582 us; speedup 1.0000x reference)
//
#include <hip/hip_runtime.h>

// Tacotron-2 style decoder, B=16, T=256, DEC=1024, ENC=256, MEL=80, ATT=128.
// R5: persistent weight-stationary kernel + QUIET barrier.
//  - R4 diagnosis: iter 69.5us with VALUBusy 14% — waiters polled 16 flag lines
//    with ACQUIRE loads every ~50ns: ~2.6TB/s of L3 same-line reads + a cache
//    invalidate per poll => L2 perpetually cold, staging starved.
//  - New barrier: store/load tree. WG w plain-stores epoch to padded slot[w];
//    WG0's 256 threads spin on one slot each (single polling WG, no storm),
//    then WG0 publishes ONE epoch line; all WGs poll that line tid==0-only at
//    s_sleep(32) (~0.85us) backoff. Exactly one release fence before arrive and
//    one acquire fence after release per iteration (same semantics as R4).
//  - k_barprobe: 64 empty barriers as a separate dispatch => direct barrier-cost
//    measurement in rocprof.
//  - Pipeline unchanged: { attn(t) || R(t-1) || LSTM1(t-2) || LSTM2(t-3) },
//    LSTM weights stationary in VGPRs, fp32 throughout.

namespace {

constexpr int TT = 256, BB = 16, LL = 256, MELD = 80, FILTD = 32, KC = 31;
constexpr int P1 = 2308;  // LSTM1 xs pitch (2304+4)
constexpr int P2 = 2052;  // LSTM2 xs pitch (2048+4)

struct Args {
  const float *enc, *spe, *mels;
  const float *Wpre1, *bpre1, *Wpre2, *bpre2, *Wsp, *bsp;
  const float *Wq, *Wm, *Wconv, *Wloc, *vatt;
  const float *Wih1, *Whh1, *bih1, *bhh1;
  const float *Wih2, *Whh2, *bih2, *bhh2;
  const float *Wmel, *bmel, *Wstop, *bstop;
  float *p, *X, *qp2, *pm2, *prevmel;
  float *h1a, *h1b, *c1, *h2a, *h2b, *c2;
  float *cum, *wexp, *uctx, *pctx, *psum, *spkvec, *spkq;
  float *W81, *b81, *tmp;
  int *slots, *epoch, *pslots, *pepoch;  // padded: slot i at [i*32]
  float *out;
};

__device__ __forceinline__ float fast_tanh(float x) {
  float ax = fabsf(x);
  float e = __expf(-2.f * ax);
  float t = (1.f - e) / (1.f + e);
  return copysignf(t, x);
}
__device__ __forceinline__ float fast_sig(float x) { return 1.f / (1.f + __expf(-x)); }

// Quiet tree barrier. target = iter+1 (monotone; slots/epoch zeroed at launch).
__device__ __forceinline__ void gridbar(int* slots, int* epoch, int target) {
  // release my data (waitcnt own stores + L2 writeback), once per iteration
  __builtin_amdgcn_fence(__ATOMIC_RELEASE, "agent");
  __syncthreads();
  if (blockIdx.x == 0) {
    if (threadIdx.x == 0)
      __hip_atomic_store(&slots[0], target, __ATOMIC_RELAXED, __HIP_MEMORY_SCOPE_AGENT);
    // 256 threads, one slot each; exec-mask reconvergence == AND over all slots
    while (__hip_atomic_load(&slots[threadIdx.x * 32], __ATOMIC_RELAXED,
                             __HIP_MEMORY_SCOPE_AGENT) < target)
      __builtin_amdgcn_s_sleep(1);
    __syncthreads();
    if (threadIdx.x == 0)
      __hip_atomic_store(epoch, target, __ATOMIC_RELEASE, __HIP_MEMORY_SCOPE_AGENT);
  } else {
    if (threadIdx.x == 0) {
      __hip_atomic_store(&slots[blockIdx.x * 32], target, __ATOMIC_RELAXED,
                         __HIP_MEMORY_SCOPE_AGENT);
      while (__hip_atomic_load(epoch, __ATOMIC_RELAXED, __HIP_MEMORY_SCOPE_AGENT) < target)
        __builtin_amdgcn_s_sleep(32);
    }
  }
  __syncthreads();
  __builtin_amdgcn_fence(__ATOMIC_ACQUIRE, "agent");
}

__global__ void k_init(float* base, int n) {
  int i = blockIdx.x * blockDim.x + threadIdx.x;
  if (i < n) base[i] = 0.f;
}

// psum[1][b][0] = 1.0 : divisor for the zeroed step-(-1) attention weights
__global__ void k_setpsum(float* psum) {
  if (threadIdx.x < 16) psum[256 + threadIdx.x * 16] = 1.f;
}

__global__ void k_prevmel(Args a) {
  int i = blockIdx.x * blockDim.x + threadIdx.x;  // (t*16+b)*80+m
  if (i >= TT * BB * MELD) return;
  int m = i % MELD;
  int tb = i / MELD;
  int b = tb & 15, t = tb >> 4;
  a.prevmel[i] = (t == 0) ? 0.f : a.mels[(b * TT + t) * MELD + m];
}

__global__ void k_spkvec(Args a) {
  int i = blockIdx.x * blockDim.x + threadIdx.x;
  if (i >= BB * 1024) return;
  int b = i >> 10, j = i & 1023;
  const float* x = a.spe + b * 256;
  const float* w = a.Wsp + j * 256;
  float s = a.bsp[j];
  for (int k = 0; k < 256; ++k) s += x[k] * w[k];
  a.spkvec[i] = s;
}

__global__ void k_spkq(Args a) {
  int i = blockIdx.x * blockDim.x + threadIdx.x;
  if (i >= BB * 128) return;
  int b = i >> 7, q = i & 127;
  const float* x = a.spkvec + b * 1024;
  const float* w = a.Wq + q * 1024;
  float s = 0.f;
  for (int k = 0; k < 1024; ++k) s += x[k] * w[k];
  a.spkq[i] = s;
}

__global__ void k_prep81(Args a) {
  int i = blockIdx.x * blockDim.x + threadIdx.x;
  if (i < 81 * 1024) {
    int r = i >> 10, k = i & 1023;
    a.W81[i] = (r < 80) ? a.Wmel[r * 1024 + k] : a.Wstop[k];
  }
  if (i < 81) a.b81[i] = (i < 80) ? a.bmel[i] : a.bstop[0];
}

// C[M,N] = act(A[M,K] @ B[N,K]^T + bias[N]); 128x64 tile, 8x4 per thread.
__global__ __launch_bounds__(256) void k_gemm(const float* __restrict__ A,
                                              const float* __restrict__ Bm,
                                              const float* __restrict__ bias,
                                              float* __restrict__ C,
                                              int M, int N, int K, int act) {
  __shared__ __align__(16) float As[16][132];
  __shared__ __align__(16) float Bs[16][68];
  const int bm = blockIdx.y * 128, bn = blockIdx.x * 64;
  const int tid = threadIdx.x;
  const int tm = (tid >> 4) * 8, tn = (tid & 15) * 4;
  float acc[8][4] = {};
  for (int k0 = 0; k0 < K; k0 += 16) {
    for (int i = tid; i < 512; i += 256) {
      int m = i >> 2, kq = i & 3;
      float4 v = *(const float4*)(A + (size_t)(bm + m) * K + k0 + kq * 4);
      As[kq * 4 + 0][m] = v.x; As[kq * 4 + 1][m] = v.y;
      As[kq * 4 + 2][m] = v.z; As[kq * 4 + 3][m] = v.w;
    }
    {
      int m = tid >> 2, kq = tid & 3;
      float4 v = *(const float4*)(Bm + (size_t)(bn + m) * K + k0 + kq * 4);
      Bs[kq * 4 + 0][m] = v.x; Bs[kq * 4 + 1][m] = v.y;
      Bs[kq * 4 + 2][m] = v.z; Bs[kq * 4 + 3][m] = v.w;
    }
    __syncthreads();
#pragma unroll
    for (int kk = 0; kk < 16; ++kk) {
      float4 a0 = *(const float4*)&As[kk][tm];
      float4 a1 = *(const float4*)&As[kk][tm + 4];
      float4 b0 = *(const float4*)&Bs[kk][tn];
      float av[8] = {a0.x, a0.y, a0.z, a0.w, a1.x, a1.y, a1.z, a1.w};
      float bv[4] = {b0.x, b0.y, b0.z, b0.w};
#pragma unroll
      for (int i = 0; i < 8; ++i)
#pragma unroll
        for (int j = 0; j < 4; ++j) acc[i][j] += av[i] * bv[j];
    }
    __syncthreads();
  }
#pragma unroll
  for (int i = 0; i < 8; ++i)
#pragma unroll
    for (int j = 0; j < 4; ++j) {
      float v = acc[i][j];
      if (bias) v += bias[bn + tn + j];
      if (act == 1) v = fmaxf(v, 0.f);
      C[(size_t)(bm + tm + i) * N + bn + tn + j] = v;
    }
}

__global__ void k_pm_transpose(Args a) {
  int i = blockIdx.x * blockDim.x + threadIdx.x;  // dest (b*128+q)*256 + l
  if (i >= BB * 128 * LL) return;
  int l = i & 255;
  int rest = i >> 8;
  int q = rest & 127, b = rest >> 7;
  a.pm2[i] = a.X[(size_t)((b << 8) + l) * 128 + q];
}

__global__ void k_addspkq(Args a) {
  int i = blockIdx.x * blockDim.x + threadIdx.x;
  if (i >= TT * BB * 128) return;
  int q = i & 127, b = (i >> 7) & 15;
  a.qp2[i] += a.spkq[b * 128 + q];
}

// barrier-cost probe: 64 empty grid barriers (separate slot/epoch arrays)
__global__ __launch_bounds__(256, 1) void k_barprobe(Args a) {
  for (int t = 0; t < 64; ++t) gridbar(a.pslots, a.pepoch, t + 1);
}

// ================= persistent decoder loop =================
// iter t: attn(t) || R(t-1) || LSTM1(t-2) || LSTM2(t-3); 259 iterations.
__global__ __launch_bounds__(256, 1) void k_persist(Args a) {
  __shared__ __align__(16) float xs[16 * P1];  // union: attn scratch / x / reduce
  __shared__ float gbuf[16][20];
  const int wg = blockIdx.x, tid = threadIdx.x;
  const int wv = tid >> 6, lane = tid & 63;
  const int d0 = wg * 4, kl = lane * 4;

  // ---- stationary weights (loaded once) ----
  float4 wL1[9][4];
  float4 wL2[8][4];
#pragma unroll
  for (int q = 0; q < 4; ++q) {
    const int row = wv * 1024 + d0 + q;
    const float* rih1 = a.Wih1 + (size_t)row * 1280;
    const float* rhh1 = a.Whh1 + (size_t)row * 1024;
    const float* rih2 = a.Wih2 + (size_t)row * 1024;
    const float* rhh2 = a.Whh2 + (size_t)row * 1024;
#pragma unroll
    for (int kb = 0; kb < 9; ++kb)
      wL1[kb][q] = (kb < 5) ? *(const float4*)(rih1 + kb * 256 + kl)
                            : *(const float4*)(rhh1 + kb * 256 + kl - 1280);
#pragma unroll
    for (int kb = 0; kb < 8; ++kb)
      wL2[kb][q] = (kb < 4) ? *(const float4*)(rih2 + kb * 256 + kl)
                            : *(const float4*)(rhh2 + kb * 256 + kl - 1024);
  }
  const int row_r = wv * 1024 + d0 + (lane >> 4);
  const float bsum1 = a.bih1[row_r] + a.bhh1[row_r];
  const float bsum2 = a.bih2[row_r] + a.bhh2[row_r];

  for (int t = 0; t < 259; ++t) {
    const int cur = t & 1, prv = cur ^ 1;

    // ---------- attention(t) ----------
    if (t < 256) {
      float* loc0 = xs;
      float* loc1 = xs + 64;
      float* F = xs + 128;     // 32 x 17
      float* expv = xs + 672;  // 16
      const int b = wg >> 4, c = wg & 15, l0 = c << 4;
      float sm = 0.f;
      {
        const float* ps = a.psum + prv * 256 + b * 16;
#pragma unroll
        for (int i = 0; i < 16; ++i) sm += ps[i];
      }
      const float inv_ps = 1.f / sm;
      if (tid < 64) {
        int lp = l0 - 16 + tid;
        bool ok = (lp >= 0 && lp < LL);
        float we = ok ? a.wexp[prv * 4096 + b * 256 + lp] * inv_ps : 0.f;
        loc0[tid] = we;
        loc1[tid] = ok ? (a.cum[prv * 4096 + b * 256 + lp] + we) : 0.f;
      }
      __syncthreads();
      // cum(t) own slice = cumulative through step t-1
      if (tid < 16) a.cum[cur * 4096 + b * 256 + l0 + tid] = loc1[16 + tid];
      for (int idx = tid; idx < FILTD * 16; idx += 256) {
        int fc = idx >> 4, ll = idx & 15;
        const float* w = a.Wconv + fc * 62;
        float s = 0.f;
#pragma unroll
        for (int k = 0; k < KC; ++k) {
          s += w[k] * loc0[ll + k + 1];
          s += w[31 + k] * loc1[ll + k + 1];
        }
        F[fc * 17 + ll] = s;
      }
      __syncthreads();
      {
        const int ll = tid >> 4, ag = tid & 15;
        const int l = l0 + ll;
        const float* qpb = a.qp2 + (size_t)((t << 4) + b) * 128;
        const float* pmb = a.pm2 + (size_t)b * 128 * 256;
        float s = 0.f;
        for (int q = ag * 8; q < ag * 8 + 8; ++q) {
          float x = qpb[q] + pmb[q * 256 + l];
          const float* wl = a.Wloc + q * 32;
#pragma unroll
          for (int fc = 0; fc < FILTD; ++fc) x += wl[fc] * F[fc * 17 + ll];
          s += a.vatt[q] * fast_tanh(x);
        }
        s += __shfl_down(s, 8, 16);
        s += __shfl_down(s, 4, 16);
        s += __shfl_down(s, 2, 16);
        s += __shfl_down(s, 1, 16);
        if (ag == 0) {
          float ex = __expf(s);  // |e| small -> no max-subtraction needed
          expv[ll] = ex;
          a.wexp[cur * 4096 + b * 256 + l] = ex;
        }
      }
      __syncthreads();
      if (tid == 0) {
        float s = 0.f;
#pragma unroll
        for (int i = 0; i < 16; ++i) s += expv[i];
        a.psum[cur * 256 + b * 16 + c] = s;  // plain store, private line
      }
      {
        float s = 0.f;
        const float* eb = a.enc + (size_t)((b << 8) + l0) * 256 + tid;
#pragma unroll
        for (int ll = 0; ll < 16; ++ll) s += expv[ll] * eb[ll * 256];
        a.pctx[cur * 65536 + (b * 16 + c) * 256 + tid] = s;  // plain store
      }
      __syncthreads();  // xs free
    }

    // ---------- R(s = t-1): reduce pctx -> normalized uctx ----------
    if (wg < 16 && t >= 1 && t <= 256) {
      const int s = t - 1, par = s & 1, b = wg;
      float sm = 0.f;
      const float* ps = a.psum + par * 256 + b * 16;
#pragma unroll
      for (int c = 0; c < 16; ++c) sm += ps[c];
      const float inv = 1.f / sm;
      float acc = 0.f;
      const float* pc = a.pctx + par * 65536 + b * 4096 + tid;
#pragma unroll
      for (int c = 0; c < 16; ++c) acc += pc[c * 256];
      a.uctx[par * 4096 + b * 256 + tid] = acc * inv;
    }

    // ---------- LSTM1(s1 = t-2) ----------
    if (t >= 2 && t <= 257) {
      const int s1 = t - 2;
      const float* pt = a.p + (size_t)s1 * 16384;
      const float* h1r = (s1 & 1) ? a.h1a : a.h1b;  // h1(s1-1)
      float* h1w = (s1 & 1) ? a.h1b : a.h1a;        // h1(s1)
      for (int i4 = tid; i4 < 4096; i4 += 256) {
        int b = i4 >> 8, kq = i4 & 255;
        *(float4*)(xs + b * P1 + kq * 4) = *(const float4*)(pt + i4 * 4);
        *(float4*)(xs + b * P1 + 1280 + kq * 4) = *(const float4*)(h1r + i4 * 4);
      }
      {
        const float* uc = a.uctx + (size_t)(s1 & 1) * 4096;
        for (int i4 = tid; i4 < 1024; i4 += 256) {
          int b = i4 >> 6, kq = i4 & 63;
          *(float4*)(xs + b * P1 + 1024 + kq * 4) = *(const float4*)(uc + i4 * 4);
        }
      }
      __syncthreads();
      float acc[4][16];
#pragma unroll
      for (int q = 0; q < 4; ++q)
#pragma unroll
        for (int b = 0; b < 16; ++b) acc[q][b] = 0.f;
#pragma unroll
      for (int kb = 0; kb < 9; ++kb) {
        const float* xb = xs + kb * 256 + kl;
#pragma unroll
        for (int b = 0; b < 16; ++b) {
          float4 x4 = *(const float4*)(xb + b * P1);
#pragma unroll
          for (int q = 0; q < 4; ++q) {
            acc[q][b] += wL1[kb][q].x * x4.x;
            acc[q][b] += wL1[kb][q].y * x4.y;
            acc[q][b] += wL1[kb][q].z * x4.z;
            acc[q][b] += wL1[kb][q].w * x4.w;
          }
        }
      }
      __syncthreads();  // xs reads done -> reuse as reduce buffer
      float* red = xs + wv * 4352;
#pragma unroll
      for (int q = 0; q < 4; ++q)
#pragma unroll
        for (int b = 0; b < 16; ++b) red[(q * 16 + b) * 68 + lane] = acc[q][b];
      __syncthreads();
      {
        const float* rr = xs + wv * 4352 + lane * 68;
        float4 s4 = {0.f, 0.f, 0.f, 0.f};
#pragma unroll
        for (int i = 0; i < 16; ++i) {
          float4 v = *(const float4*)(rr + i * 4);
          s4.x += v.x; s4.y += v.y; s4.z += v.z; s4.w += v.w;
        }
        gbuf[wv * 4 + (lane >> 4)][lane & 15] = s4.x + s4.y + s4.z + s4.w + bsum1;
      }
      __syncthreads();
      if (tid < 64) {
        int dd = tid >> 4, b = tid & 15;
        int d = d0 + dd;
        float gi = gbuf[0 + dd][b], gf = gbuf[4 + dd][b];
        float gg = gbuf[8 + dd][b], go = gbuf[12 + dd][b];
        float co = a.c1[b * 1024 + d];
        float cn = fast_sig(gf) * co + fast_sig(gi) * fast_tanh(gg);
        float hn = fast_sig(go) * fast_tanh(cn);
        a.c1[b * 1024 + d] = cn;
        h1w[b * 1024 + d] = hn;
      }
      __syncthreads();
    }

    // ---------- LSTM2(s2 = t-3) ----------
    if (t >= 3) {
      const int s2 = t - 3;
      const float* h1s = (s2 & 1) ? a.h1b : a.h1a;  // h1(s2)
      const float* h2r = (s2 & 1) ? a.h2a : a.h2b;  // h2(s2-1)
      float* h2w = (s2 & 1) ? a.h2b : a.h2a;        // h2(s2)
      for (int i4 = tid; i4 < 4096; i4 += 256) {
        int b = i4 >> 8, kq = i4 & 255;
        *(float4*)(xs + b * P2 + kq * 4) = *(const float4*)(h1s + i4 * 4);
        *(float4*)(xs + b * P2 + 1024 + kq * 4) = *(const float4*)(h2r + i4 * 4);
      }
      __syncthreads();
      float acc[4][16];
#pragma unroll
      for (int q = 0; q < 4; ++q)
#pragma unroll
        for (int b = 0; b < 16; ++b) acc[q][b] = 0.f;
#pragma unroll
      for (int kb = 0; kb < 8; ++kb) {
        const float* xb = xs + kb * 256 + kl;
#pragma unroll
        for (int b = 0; b < 16; ++b) {
          float4 x4 = *(const float4*)(xb + b * P2);
#pragma unroll
          for (int q = 0; q < 4; ++q) {
            acc[q][b] += wL2[kb][q].x * x4.x;
            acc[q][b] += wL2[kb][q].y * x4.y;
            acc[q][b] += wL2[kb][q].z * x4.z;
            acc[q][b] += wL2[kb][q].w * x4.w;
          }
        }
      }
      __syncthreads();
      float* red = xs + wv * 4352;
#pragma unroll
      for (int q = 0; q < 4; ++q)
#pragma unroll
        for (int b = 0; b < 16; ++b) red[(q * 16 + b) * 68 + lane] = acc[q][b];
      __syncthreads();
      {
        const float* rr = xs + wv * 4352 + lane * 68;
        float4 s4 = {0.f, 0.f, 0.f, 0.f};
#pragma unroll
        for (int i = 0; i < 16; ++i) {
          float4 v = *(const float4*)(rr + i * 4);
          s4.x += v.x; s4.y += v.y; s4.z += v.z; s4.w += v.w;
        }
        gbuf[wv * 4 + (lane >> 4)][lane & 15] = s4.x + s4.y + s4.z + s4.w + bsum2;
      }
      __syncthreads();
      if (tid < 64) {
        int dd = tid >> 4, b = tid & 15;
        int d = d0 + dd;
        float gi = gbuf[0 + dd][b], gf = gbuf[4 + dd][b];
        float gg = gbuf[8 + dd][b], go = gbuf[12 + dd][b];
        float co = a.c2[b * 1024 + d];
        float cn = fast_sig(gf) * co + fast_sig(gi) * fast_tanh(gg);
        float hn = fast_sig(go) * fast_tanh(cn);
        a.c2[b * 1024 + d] = cn;
        h2w[b * 1024 + d] = hn;
        a.X[(size_t)(s2 * 16 + b) * 1024 + d] = hn;  // h2_all for epilogue
      }
    }

    if (t < 258) gridbar(a.slots, a.epoch, t + 1);
  }
}

__global__ void k_finish(Args a) {
  int i = blockIdx.x * blockDim.x + threadIdx.x;  // tb*128+col
  if (i >= 4096 * 128) return;
  int col = i & 127, tb = i >> 7;
  int t = tb >> 4, b = tb & 15;
  float v = a.tmp[i];
  if (col < 80) a.out[(size_t)(b * 256 + t) * 80 + col] = v;
  else if (col == 80) a.out[327680 + b * 256 + t] = fast_sig(v);
}

}  // namespace

extern "C" void kernel_launch(void* const* d_in, const int* in_sizes, int n_in,
                              void* d_out, int out_size, void* d_ws, size_t ws_size,
                              hipStream_t stream) {
  float* ws = (float*)d_ws;
  Args a;
  a.enc = (const float*)d_in[0];
  a.spe = (const float*)d_in[1];
  a.mels = (const float*)d_in[2];
  a.Wpre1 = (const float*)d_in[3];  a.bpre1 = (const float*)d_in[4];
  a.Wpre2 = (const float*)d_in[5];  a.bpre2 = (const float*)d_in[6];
  a.Wsp = (const float*)d_in[7];    a.bsp = (const float*)d_in[8];
  a.Wq = (const float*)d_in[9];     a.Wm = (const float*)d_in[10];
  a.Wconv = (const float*)d_in[11]; a.Wloc = (const float*)d_in[12];
  a.vatt = (const float*)d_in[13];
  a.Wih1 = (const float*)d_in[14];  a.Whh1 = (const float*)d_in[15];
  a.bih1 = (const float*)d_in[16];  a.bhh1 = (const float*)d_in[17];
  a.Wih2 = (const float*)d_in[18];  a.Whh2 = (const float*)d_in[19];
  a.bih2 = (const float*)d_in[20];  a.bhh2 = (const float*)d_in[21];
  a.Wmel = (const float*)d_in[22];  a.bmel = (const float*)d_in[23];
  a.Wstop = (const float*)d_in[24]; a.bstop = (const float*)d_in[25];

  // ws layout (floats), total 10,382,016 floats ~= 41.5 MB
  a.p    = ws + 0;         // 4096x1024
  a.X    = ws + 4194304;   // prenet hidden -> pm temp -> h2_all
  a.qp2  = ws + 8388608;   // 4096x128
  a.pm2  = ws + 8912896;   // 16x128x256
  float* st = ws + 9437184;  // STATE block, 270,912 floats (zeroed each launch)
  a.h1a = st + 0;      a.h1b = st + 16384;
  a.c1  = st + 32768;
  a.h2a = st + 49152;  a.h2b = st + 65536;
  a.c2  = st + 81920;
  a.cum  = st + 98304;    // [2][16][256]
  a.wexp = st + 106496;   // [2][16][256]
  a.uctx = st + 114688;   // [2][16][256]
  a.pctx = st + 122880;   // [2][16][16][256]
  a.psum = st + 253952;   // [2][16][16]
  a.slots  = (int*)(st + 254464);  // 256 slots x 32-int pad
  a.epoch  = (int*)(st + 262656);  // 1 x 32-int pad
  a.pslots = (int*)(st + 262688);  // probe: 256 x 32
  a.pepoch = (int*)(st + 270880);  // probe: 1 x 32
  a.spkvec = ws + 9708096;  // 16x1024
  a.spkq   = ws + 9724480;  // 16x128
  a.W81    = ws + 9726528;  // 128x1024 (rows 81..127 unused)
  a.b81    = ws + 9857600;  // 128
  a.tmp    = ws + 9857728;  // 4096x128
  a.prevmel = a.tmp;        // prologue-only, aliases epilogue tmp
  a.out = (float*)d_out;

  k_init<<<(270912 + 255) / 256, 256, 0, stream>>>(st, 270912);
  k_setpsum<<<1, 64, 0, stream>>>(a.psum);
  k_prevmel<<<(TT * BB * MELD + 255) / 256, 256, 0, stream>>>(a);
  k_spkvec<<<(BB * 1024 + 255) / 256, 256, 0, stream>>>(a);
  k_spkq<<<(BB * 128 + 255) / 256, 256, 0, stream>>>(a);
  k_prep81<<<(81 * 1024 + 255) / 256, 256, 0, stream>>>(a);

  // prenet1 -> X (temp), prenet2 -> p
  k_gemm<<<dim3(16, 32), 256, 0, stream>>>(a.prevmel, a.Wpre1, a.bpre1, a.X, 4096, 1024, 80, 1);
  k_gemm<<<dim3(16, 32), 256, 0, stream>>>(a.X, a.Wpre2, a.bpre2, a.p, 4096, 1024, 1024, 1);
  // qp2 = p @ Wq^T (+ spk @ Wq^T)
  k_gemm<<<dim3(2, 32), 256, 0, stream>>>(a.p, a.Wq, nullptr, a.qp2, 4096, 128, 1024, 0);
  k_addspkq<<<(TT * BB * 128 + 255) / 256, 256, 0, stream>>>(a);
  // proc_mem = enc @ Wm^T -> X temp -> transpose to [b][att][l]
  k_gemm<<<dim3(2, 32), 256, 0, stream>>>(a.enc, a.Wm, nullptr, a.X, 4096, 128, 256, 0);
  k_pm_transpose<<<(BB * 128 * LL + 255) / 256, 256, 0, stream>>>(a);

  // barrier-cost probe (64 empty barriers) — rocprof-visible as its own dispatch
  {
    void* kargs[] = {(void*)&a};
    hipError_t e = hipLaunchCooperativeKernel(reinterpret_cast<const void*>(&k_barprobe),
                                              dim3(256), dim3(256), kargs, 0, stream);
    if (e != hipSuccess) k_barprobe<<<256, 256, 0, stream>>>(a);
  }

  // persistent decoder: 256 WGs (1/CU), cooperative; fallback to plain launch
  {
    void* kargs[] = {(void*)&a};
    hipError_t e = hipLaunchCooperativeKernel(reinterpret_cast<const void*>(&k_persist),
                                              dim3(256), dim3(256), kargs, 0, stream);
    if (e != hipSuccess) k_persist<<<256, 256, 0, stream>>>(a);
  }

  // mel/stop projection: h2_all @ W81^T -> tmp, then scatter
  k_gemm<<<dim3(2, 32), 256, 0, stream>>>(a.X, a.W81, a.b81, a.tmp, 4096, 128, 1024, 0);
  k_finish<<<(4096 * 128 + 255) / 256, 256, 0, stream>>>(a);
}

// Round 6
// 17587.624 us; speedup vs baseline: 1.1657x; 1.1657x over previous
//
#include <hip/hip_runtime.h>

// Tacotron-2 style decoder, B=16, T=256, DEC=1024, ENC=256, MEL=80, ATT=128.
// R6: persistent weight-stationary kernel, FENCE-FREE coherent communication.
//  - R2..R5 all converge at ~70us/step regardless of sync mechanism; common factor
//    = per-step agent fences (buffer_wbl2 L2 dirty-walk + buffer_inv flash-invalidate)
//    or kernel-boundary equivalents -> L2 cold every iteration, all reads at L3/HBM
//    latency with 1 wave/SIMD.
//  - Fix: NO fences at all. The ~450KB mutable cross-WG state (h1/h2, wexp, cum,
//    psum, pctx, uctx) is accessed only with relaxed AGENT-scope atomic ops
//    (write-through / L2-bypassing -> L3 is the coherence point). All read-only
//    data (p, qp2, pm2, enc) stays plainly cached and stays WARM in L2.
//  - Ordering: __syncthreads() inside the barrier drains each wave's vmcnt
//    (stores acked at L3) before the relaxed barrier signal; consumers' coherent
//    loads happen after the relaxed epoch read.
//  - k_barprobe: 512 empty barriers -> if the barrier is expensive it shows up
//    as a multi-ms dispatch in the profile (tripwire).
//  - Pipeline unchanged: { attn(t) || R(t-1) || LSTM1(t-2) || LSTM2(t-3) },
//    LSTM weights stationary in VGPRs, fp32 throughout.

namespace {

constexpr int TT = 256, BB = 16, LL = 256, MELD = 80, FILTD = 32, KC = 31;
constexpr int P1 = 2308;  // LSTM1 xs pitch (2304+4)
constexpr int P2 = 2052;  // LSTM2 xs pitch (2048+4)

struct Args {
  const float *enc, *spe, *mels;
  const float *Wpre1, *bpre1, *Wpre2, *bpre2, *Wsp, *bsp;
  const float *Wq, *Wm, *Wconv, *Wloc, *vatt;
  const float *Wih1, *Whh1, *bih1, *bhh1;
  const float *Wih2, *Whh2, *bih2, *bhh2;
  const float *Wmel, *bmel, *Wstop, *bstop;
  float *p, *X, *qp2, *pm2, *prevmel;
  float *h1a, *h1b, *c1, *h2a, *h2b, *c2;
  float *cum, *wexp, *uctx, *pctx, *psum, *spkvec, *spkq;
  float *W81, *b81, *tmp;
  int *slots, *epoch, *pslots, *pepoch;  // padded: slot i at [i*32]
  float *out;
};

__device__ __forceinline__ float fast_tanh(float x) {
  float ax = fabsf(x);
  float e = __expf(-2.f * ax);
  float t = (1.f - e) / (1.f + e);
  return copysignf(t, x);
}
__device__ __forceinline__ float fast_sig(float x) { return 1.f / (1.f + __expf(-x)); }

// ---- device-coherent (L3 point-of-coherence) access, no fences ----
__device__ __forceinline__ float cload(const float* p) {
  return __hip_atomic_load(p, __ATOMIC_RELAXED, __HIP_MEMORY_SCOPE_AGENT);
}
__device__ __forceinline__ void cstore(float* p, float v) {
  __hip_atomic_store(p, v, __ATOMIC_RELAXED, __HIP_MEMORY_SCOPE_AGENT);
}
__device__ __forceinline__ float2 cload2(const float* p) {
  union { unsigned long long u; float2 f; } c;
  c.u = __hip_atomic_load((const unsigned long long*)p, __ATOMIC_RELAXED,
                          __HIP_MEMORY_SCOPE_AGENT);
  return c.f;
}

// Fence-free tree barrier. target = iter+1 (monotone; slots/epoch zeroed at launch).
// __syncthreads() drains each wave's vmcnt -> this WG's write-through stores are
// at the coherence point before tid0 signals.
__device__ __forceinline__ void gridbar(int* slots, int* epoch, int target) {
  __syncthreads();
  if (blockIdx.x == 0) {
    if (threadIdx.x == 0)
      __hip_atomic_store(&slots[0], target, __ATOMIC_RELAXED, __HIP_MEMORY_SCOPE_AGENT);
    while (__hip_atomic_load(&slots[threadIdx.x * 32], __ATOMIC_RELAXED,
                             __HIP_MEMORY_SCOPE_AGENT) < target)
      __builtin_amdgcn_s_sleep(1);
    __syncthreads();
    if (threadIdx.x == 0)
      __hip_atomic_store(epoch, target, __ATOMIC_RELAXED, __HIP_MEMORY_SCOPE_AGENT);
  } else {
    if (threadIdx.x == 0) {
      __hip_atomic_store(&slots[blockIdx.x * 32], target, __ATOMIC_RELAXED,
                         __HIP_MEMORY_SCOPE_AGENT);
      while (__hip_atomic_load(epoch, __ATOMIC_RELAXED, __HIP_MEMORY_SCOPE_AGENT) < target)
        __builtin_amdgcn_s_sleep(8);
    }
  }
  __syncthreads();
  asm volatile("" ::: "memory");  // keep coherent loads after the poll
}

__global__ void k_init(float* base, int n) {
  int i = blockIdx.x * blockDim.x + threadIdx.x;
  if (i < n) base[i] = 0.f;
}

// psum[1][b][0] = 1.0 : divisor for the zeroed step-(-1) attention weights
__global__ void k_setpsum(float* psum) {
  if (threadIdx.x < 16) psum[256 + threadIdx.x * 16] = 1.f;
}

__global__ void k_prevmel(Args a) {
  int i = blockIdx.x * blockDim.x + threadIdx.x;  // (t*16+b)*80+m
  if (i >= TT * BB * MELD) return;
  int m = i % MELD;
  int tb = i / MELD;
  int b = tb & 15, t = tb >> 4;
  a.prevmel[i] = (t == 0) ? 0.f : a.mels[(b * TT + t) * MELD + m];
}

__global__ void k_spkvec(Args a) {
  int i = blockIdx.x * blockDim.x + threadIdx.x;
  if (i >= BB * 1024) return;
  int b = i >> 10, j = i & 1023;
  const float* x = a.spe + b * 256;
  const float* w = a.Wsp + j * 256;
  float s = a.bsp[j];
  for (int k = 0; k < 256; ++k) s += x[k] * w[k];
  a.spkvec[i] = s;
}

__global__ void k_spkq(Args a) {
  int i = blockIdx.x * blockDim.x + threadIdx.x;
  if (i >= BB * 128) return;
  int b = i >> 7, q = i & 127;
  const float* x = a.spkvec + b * 1024;
  const float* w = a.Wq + q * 1024;
  float s = 0.f;
  for (int k = 0; k < 1024; ++k) s += x[k] * w[k];
  a.spkq[i] = s;
}

__global__ void k_prep81(Args a) {
  int i = blockIdx.x * blockDim.x + threadIdx.x;
  if (i < 81 * 1024) {
    int r = i >> 10, k = i & 1023;
    a.W81[i] = (r < 80) ? a.Wmel[r * 1024 + k] : a.Wstop[k];
  }
  if (i < 81) a.b81[i] = (i < 80) ? a.bmel[i] : a.bstop[0];
}

// C[M,N] = act(A[M,K] @ B[N,K]^T + bias[N]); 128x64 tile, 8x4 per thread.
__global__ __launch_bounds__(256) void k_gemm(const float* __restrict__ A,
                                              const float* __restrict__ Bm,
                                              const float* __restrict__ bias,
                                              float* __restrict__ C,
                                              int M, int N, int K, int act) {
  __shared__ __align__(16) float As[16][132];
  __shared__ __align__(16) float Bs[16][68];
  const int bm = blockIdx.y * 128, bn = blockIdx.x * 64;
  const int tid = threadIdx.x;
  const int tm = (tid >> 4) * 8, tn = (tid & 15) * 4;
  float acc[8][4] = {};
  for (int k0 = 0; k0 < K; k0 += 16) {
    for (int i = tid; i < 512; i += 256) {
      int m = i >> 2, kq = i & 3;
      float4 v = *(const float4*)(A + (size_t)(bm + m) * K + k0 + kq * 4);
      As[kq * 4 + 0][m] = v.x; As[kq * 4 + 1][m] = v.y;
      As[kq * 4 + 2][m] = v.z; As[kq * 4 + 3][m] = v.w;
    }
    {
      int m = tid >> 2, kq = tid & 3;
      float4 v = *(const float4*)(Bm + (size_t)(bn + m) * K + k0 + kq * 4);
      Bs[kq * 4 + 0][m] = v.x; Bs[kq * 4 + 1][m] = v.y;
      Bs[kq * 4 + 2][m] = v.z; Bs[kq * 4 + 3][m] = v.w;
    }
    __syncthreads();
#pragma unroll
    for (int kk = 0; kk < 16; ++kk) {
      float4 a0 = *(const float4*)&As[kk][tm];
      float4 a1 = *(const float4*)&As[kk][tm + 4];
      float4 b0 = *(const float4*)&Bs[kk][tn];
      float av[8] = {a0.x, a0.y, a0.z, a0.w, a1.x, a1.y, a1.z, a1.w};
      float bv[4] = {b0.x, b0.y, b0.z, b0.w};
#pragma unroll
      for (int i = 0; i < 8; ++i)
#pragma unroll
        for (int j = 0; j < 4; ++j) acc[i][j] += av[i] * bv[j];
    }
    __syncthreads();
  }
#pragma unroll
  for (int i = 0; i < 8; ++i)
#pragma unroll
    for (int j = 0; j < 4; ++j) {
      float v = acc[i][j];
      if (bias) v += bias[bn + tn + j];
      if (act == 1) v = fmaxf(v, 0.f);
      C[(size_t)(bm + tm + i) * N + bn + tn + j] = v;
    }
}

__global__ void k_pm_transpose(Args a) {
  int i = blockIdx.x * blockDim.x + threadIdx.x;  // dest (b*128+q)*256 + l
  if (i >= BB * 128 * LL) return;
  int l = i & 255;
  int rest = i >> 8;
  int q = rest & 127, b = rest >> 7;
  a.pm2[i] = a.X[(size_t)((b << 8) + l) * 128 + q];
}

__global__ void k_addspkq(Args a) {
  int i = blockIdx.x * blockDim.x + threadIdx.x;
  if (i >= TT * BB * 128) return;
  int q = i & 127, b = (i >> 7) & 15;
  a.qp2[i] += a.spkq[b * 128 + q];
}

// barrier-cost probe: 512 empty grid barriers (tripwire: multi-ms if barrier is slow)
__global__ __launch_bounds__(256, 1) void k_barprobe(Args a) {
  for (int t = 0; t < 512; ++t) gridbar(a.pslots, a.pepoch, t + 1);
}

// ================= persistent decoder loop =================
// iter t: attn(t) || R(t-1) || LSTM1(t-2) || LSTM2(t-3); 259 iterations.
__global__ __launch_bounds__(256, 1) void k_persist(Args a) {
  __shared__ __align__(16) float xs[16 * P1];  // union: attn scratch / x / reduce
  __shared__ float gbuf[16][20];
  const int wg = blockIdx.x, tid = threadIdx.x;
  const int wv = tid >> 6, lane = tid & 63;
  const int d0 = wg * 4, kl = lane * 4;

  // ---- stationary weights (loaded once, plain cached) ----
  float4 wL1[9][4];
  float4 wL2[8][4];
#pragma unroll
  for (int q = 0; q < 4; ++q) {
    const int row = wv * 1024 + d0 + q;
    const float* rih1 = a.Wih1 + (size_t)row * 1280;
    const float* rhh1 = a.Whh1 + (size_t)row * 1024;
    const float* rih2 = a.Wih2 + (size_t)row * 1024;
    const float* rhh2 = a.Whh2 + (size_t)row * 1024;
#pragma unroll
    for (int kb = 0; kb < 9; ++kb)
      wL1[kb][q] = (kb < 5) ? *(const float4*)(rih1 + kb * 256 + kl)
                            : *(const float4*)(rhh1 + kb * 256 + kl - 1280);
#pragma unroll
    for (int kb = 0; kb < 8; ++kb)
      wL2[kb][q] = (kb < 4) ? *(const float4*)(rih2 + kb * 256 + kl)
                            : *(const float4*)(rhh2 + kb * 256 + kl - 1024);
  }
  const int row_r = wv * 1024 + d0 + (lane >> 4);
  const float bsum1 = a.bih1[row_r] + a.bhh1[row_r];
  const float bsum2 = a.bih2[row_r] + a.bhh2[row_r];

  for (int t = 0; t < 259; ++t) {
    const int cur = t & 1, prv = cur ^ 1;

    // ---------- attention(t) ----------
    if (t < 256) {
      float* loc0 = xs;
      float* loc1 = xs + 64;
      float* F = xs + 128;     // 32 x 17
      float* expv = xs + 672;  // 16
      float* psv = xs + 688;   // 16
      const int b = wg >> 4, c = wg & 15, l0 = c << 4;
      if (tid < 16) psv[tid] = cload(a.psum + prv * 256 + b * 16 + tid);
      __syncthreads();
      float sm = 0.f;
#pragma unroll
      for (int i = 0; i < 16; ++i) sm += psv[i];
      const float inv_ps = 1.f / sm;
      if (tid < 64) {
        int lp = l0 - 16 + tid;
        bool ok = (lp >= 0 && lp < LL);
        float we = ok ? cload(a.wexp + prv * 4096 + b * 256 + lp) * inv_ps : 0.f;
        loc0[tid] = we;
        loc1[tid] = ok ? (cload(a.cum + prv * 4096 + b * 256 + lp) + we) : 0.f;
      }
      __syncthreads();
      // cum(t) own slice = cumulative through step t-1
      if (tid < 16) cstore(a.cum + cur * 4096 + b * 256 + l0 + tid, loc1[16 + tid]);
      for (int idx = tid; idx < FILTD * 16; idx += 256) {
        int fc = idx >> 4, ll = idx & 15;
        const float* w = a.Wconv + fc * 62;
        float s = 0.f;
#pragma unroll
        for (int k = 0; k < KC; ++k) {
          s += w[k] * loc0[ll + k + 1];
          s += w[31 + k] * loc1[ll + k + 1];
        }
        F[fc * 17 + ll] = s;
      }
      __syncthreads();
      {
        const int ll = tid >> 4, ag = tid & 15;
        const int l = l0 + ll;
        const float* qpb = a.qp2 + (size_t)((t << 4) + b) * 128;
        const float* pmb = a.pm2 + (size_t)b * 128 * 256;
        float s = 0.f;
        for (int q = ag * 8; q < ag * 8 + 8; ++q) {
          float x = qpb[q] + pmb[q * 256 + l];
          const float* wl = a.Wloc + q * 32;
#pragma unroll
          for (int fc = 0; fc < FILTD; ++fc) x += wl[fc] * F[fc * 17 + ll];
          s += a.vatt[q] * fast_tanh(x);
        }
        s += __shfl_down(s, 8, 16);
        s += __shfl_down(s, 4, 16);
        s += __shfl_down(s, 2, 16);
        s += __shfl_down(s, 1, 16);
        if (ag == 0) {
          float ex = __expf(s);  // |e| small -> no max-subtraction needed
          expv[ll] = ex;
          cstore(a.wexp + cur * 4096 + b * 256 + l, ex);
        }
      }
      __syncthreads();
      if (tid == 0) {
        float s = 0.f;
#pragma unroll
        for (int i = 0; i < 16; ++i) s += expv[i];
        cstore(a.psum + cur * 256 + b * 16 + c, s);
      }
      {
        float s = 0.f;
        const float* eb = a.enc + (size_t)((b << 8) + l0) * 256 + tid;
#pragma unroll
        for (int ll = 0; ll < 16; ++ll) s += expv[ll] * eb[ll * 256];
        cstore(a.pctx + cur * 65536 + (b * 16 + c) * 256 + tid, s);
      }
      __syncthreads();  // xs free
    }

    // ---------- R(s = t-1): reduce pctx -> normalized uctx ----------
    if (wg < 16 && t >= 1 && t <= 256) {
      const int s = t - 1, par = s & 1, b = wg;
      float sm = 0.f;
      const float* ps = a.psum + par * 256 + b * 16;
#pragma unroll
      for (int c = 0; c < 16; ++c) sm += cload(ps + c);
      const float inv = 1.f / sm;
      float acc = 0.f;
      const float* pc = a.pctx + par * 65536 + b * 4096 + tid;
#pragma unroll
      for (int c = 0; c < 16; ++c) acc += cload(pc + c * 256);
      cstore(a.uctx + par * 4096 + b * 256 + tid, acc * inv);
    }

    // ---------- LSTM1(s1 = t-2) ----------
    if (t >= 2 && t <= 257) {
      const int s1 = t - 2;
      const float* pt = a.p + (size_t)s1 * 16384;
      const float* h1r = (s1 & 1) ? a.h1a : a.h1b;  // h1(s1-1)
      float* h1w = (s1 & 1) ? a.h1b : a.h1a;        // h1(s1)
      for (int i4 = tid; i4 < 4096; i4 += 256) {    // p: plain cached (read-only)
        int b = i4 >> 8, kq = i4 & 255;
        *(float4*)(xs + b * P1 + kq * 4) = *(const float4*)(pt + i4 * 4);
      }
      for (int i2 = tid; i2 < 8192; i2 += 256) {    // h1: coherent 8B
        int b = i2 >> 9, k2 = (i2 & 511) * 2;
        *(float2*)(xs + b * P1 + 1280 + k2) = cload2(h1r + b * 1024 + k2);
      }
      {
        const float* uc = a.uctx + (size_t)(s1 & 1) * 4096;  // already normalized
        for (int i2 = tid; i2 < 2048; i2 += 256) {  // uctx: coherent 8B
          int b = i2 >> 7, k2 = (i2 & 127) * 2;
          *(float2*)(xs + b * P1 + 1024 + k2) = cload2(uc + b * 256 + k2);
        }
      }
      __syncthreads();
      float acc[4][16];
#pragma unroll
      for (int q = 0; q < 4; ++q)
#pragma unroll
        for (int b = 0; b < 16; ++b) acc[q][b] = 0.f;
#pragma unroll
      for (int kb = 0; kb < 9; ++kb) {
        const float* xb = xs + kb * 256 + kl;
#pragma unroll
        for (int b = 0; b < 16; ++b) {
          float4 x4 = *(const float4*)(xb + b * P1);
#pragma unroll
          for (int q = 0; q < 4; ++q) {
            acc[q][b] += wL1[kb][q].x * x4.x;
            acc[q][b] += wL1[kb][q].y * x4.y;
            acc[q][b] += wL1[kb][q].z * x4.z;
            acc[q][b] += wL1[kb][q].w * x4.w;
          }
        }
      }
      __syncthreads();  // xs reads done -> reuse as reduce buffer
      float* red = xs + wv * 4352;
#pragma unroll
      for (int q = 0; q < 4; ++q)
#pragma unroll
        for (int b = 0; b < 16; ++b) red[(q * 16 + b) * 68 + lane] = acc[q][b];
      __syncthreads();
      {
        const float* rr = xs + wv * 4352 + lane * 68;
        float4 s4 = {0.f, 0.f, 0.f, 0.f};
#pragma unroll
        for (int i = 0; i < 16; ++i) {
          float4 v = *(const float4*)(rr + i * 4);
          s4.x += v.x; s4.y += v.y; s4.z += v.z; s4.w += v.w;
        }
        gbuf[wv * 4 + (lane >> 4)][lane & 15] = s4.x + s4.y + s4.z + s4.w + bsum1;
      }
      __syncthreads();
      if (tid < 64) {
        int dd = tid >> 4, b = tid & 15;
        int d = d0 + dd;
        float gi = gbuf[0 + dd][b], gf = gbuf[4 + dd][b];
        float gg = gbuf[8 + dd][b], go = gbuf[12 + dd][b];
        float co = a.c1[b * 1024 + d];                  // private: plain cached
        float cn = fast_sig(gf) * co + fast_sig(gi) * fast_tanh(gg);
        float hn = fast_sig(go) * fast_tanh(cn);
        a.c1[b * 1024 + d] = cn;
        cstore(h1w + b * 1024 + d, hn);                 // cross-WG: coherent
      }
      __syncthreads();
    }

    // ---------- LSTM2(s2 = t-3) ----------
    if (t >= 3) {
      const int s2 = t - 3;
      const float* h1s = (s2 & 1) ? a.h1b : a.h1a;  // h1(s2)
      const float* h2r = (s2 & 1) ? a.h2a : a.h2b;  // h2(s2-1)
      float* h2w = (s2 & 1) ? a.h2b : a.h2a;        // h2(s2)
      for (int i2 = tid; i2 < 8192; i2 += 256) {    // h1,h2: coherent 8B
        int b = i2 >> 9, k2 = (i2 & 511) * 2;
        *(float2*)(xs + b * P2 + k2) = cload2(h1s + b * 1024 + k2);
        *(float2*)(xs + b * P2 + 1024 + k2) = cload2(h2r + b * 1024 + k2);
      }
      __syncthreads();
      float acc[4][16];
#pragma unroll
      for (int q = 0; q < 4; ++q)
#pragma unroll
        for (int b = 0; b < 16; ++b) acc[q][b] = 0.f;
#pragma unroll
      for (int kb = 0; kb < 8; ++kb) {
        const float* xb = xs + kb * 256 + kl;
#pragma unroll
        for (int b = 0; b < 16; ++b) {
          float4 x4 = *(const float4*)(xb + b * P2);
#pragma unroll
          for (int q = 0; q < 4; ++q) {
            acc[q][b] += wL2[kb][q].x * x4.x;
            acc[q][b] += wL2[kb][q].y * x4.y;
            acc[q][b] += wL2[kb][q].z * x4.z;
            acc[q][b] += wL2[kb][q].w * x4.w;
          }
        }
      }
      __syncthreads();
      float* red = xs + wv * 4352;
#pragma unroll
      for (int q = 0; q < 4; ++q)
#pragma unroll
        for (int b = 0; b < 16; ++b) red[(q * 16 + b) * 68 + lane] = acc[q][b];
      __syncthreads();
      {
        const float* rr = xs + wv * 4352 + lane * 68;
        float4 s4 = {0.f, 0.f, 0.f, 0.f};
#pragma unroll
        for (int i = 0; i < 16; ++i) {
          float4 v = *(const float4*)(rr + i * 4);
          s4.x += v.x; s4.y += v.y; s4.z += v.z; s4.w += v.w;
        }
        gbuf[wv * 4 + (lane >> 4)][lane & 15] = s4.x + s4.y + s4.z + s4.w + bsum2;
      }
      __syncthreads();
      if (tid < 64) {
        int dd = tid >> 4, b = tid & 15;
        int d = d0 + dd;
        float gi = gbuf[0 + dd][b], gf = gbuf[4 + dd][b];
        float gg = gbuf[8 + dd][b], go = gbuf[12 + dd][b];
        float co = a.c2[b * 1024 + d];                  // private: plain cached
        float cn = fast_sig(gf) * co + fast_sig(gi) * fast_tanh(gg);
        float hn = fast_sig(go) * fast_tanh(cn);
        a.c2[b * 1024 + d] = cn;
        cstore(h2w + b * 1024 + d, hn);                 // cross-WG: coherent
        a.X[(size_t)(s2 * 16 + b) * 1024 + d] = hn;     // epilogue-only: plain
      }
    }

    if (t < 258) gridbar(a.slots, a.epoch, t + 1);
  }
}

__global__ void k_finish(Args a) {
  int i = blockIdx.x * blockDim.x + threadIdx.x;  // tb*128+col
  if (i >= 4096 * 128) return;
  int col = i & 127, tb = i >> 7;
  int t = tb >> 4, b = tb & 15;
  float v = a.tmp[i];
  if (col < 80) a.out[(size_t)(b * 256 + t) * 80 + col] = v;
  else if (col == 80) a.out[327680 + b * 256 + t] = fast_sig(v);
}

}  // namespace

extern "C" void kernel_launch(void* const* d_in, const int* in_sizes, int n_in,
                              void* d_out, int out_size, void* d_ws, size_t ws_size,
                              hipStream_t stream) {
  float* ws = (float*)d_ws;
  Args a;
  a.enc = (const float*)d_in[0];
  a.spe = (const float*)d_in[1];
  a.mels = (const float*)d_in[2];
  a.Wpre1 = (const float*)d_in[3];  a.bpre1 = (const float*)d_in[4];
  a.Wpre2 = (const float*)d_in[5];  a.bpre2 = (const float*)d_in[6];
  a.Wsp = (const float*)d_in[7];    a.bsp = (const float*)d_in[8];
  a.Wq = (const float*)d_in[9];     a.Wm = (const float*)d_in[10];
  a.Wconv = (const float*)d_in[11]; a.Wloc = (const float*)d_in[12];
  a.vatt = (const float*)d_in[13];
  a.Wih1 = (const float*)d_in[14];  a.Whh1 = (const float*)d_in[15];
  a.bih1 = (const float*)d_in[16];  a.bhh1 = (const float*)d_in[17];
  a.Wih2 = (const float*)d_in[18];  a.Whh2 = (const float*)d_in[19];
  a.bih2 = (const float*)d_in[20];  a.bhh2 = (const float*)d_in[21];
  a.Wmel = (const float*)d_in[22];  a.bmel = (const float*)d_in[23];
  a.Wstop = (const float*)d_in[24]; a.bstop = (const float*)d_in[25];

  // ws layout (floats), total 10,382,016 floats ~= 41.5 MB
  a.p    = ws + 0;         // 4096x1024
  a.X    = ws + 4194304;   // prenet hidden -> pm temp -> h2_all
  a.qp2  = ws + 8388608;   // 4096x128
  a.pm2  = ws + 8912896;   // 16x128x256
  float* st = ws + 9437184;  // STATE block, 270,912 floats (zeroed each launch)
  a.h1a = st + 0;      a.h1b = st + 16384;
  a.c1  = st + 32768;
  a.h2a = st + 49152;  a.h2b = st + 65536;
  a.c2  = st + 81920;
  a.cum  = st + 98304;    // [2][16][256]
  a.wexp = st + 106496;   // [2][16][256]
  a.uctx = st + 114688;   // [2][16][256]
  a.pctx = st + 122880;   // [2][16][16][256]
  a.psum = st + 253952;   // [2][16][16]
  a.slots  = (int*)(st + 254464);  // 256 slots x 32-int pad
  a.epoch  = (int*)(st + 262656);  // 1 x 32-int pad
  a.pslots = (int*)(st + 262688);  // probe: 256 x 32
  a.pepoch = (int*)(st + 270880);  // probe: 1 x 32
  a.spkvec = ws + 9708096;  // 16x1024
  a.spkq   = ws + 9724480;  // 16x128
  a.W81    = ws + 9726528;  // 128x1024 (rows 81..127 unused)
  a.b81    = ws + 9857600;  // 128
  a.tmp    = ws + 9857728;  // 4096x128
  a.prevmel = a.tmp;        // prologue-only, aliases epilogue tmp
  a.out = (float*)d_out;

  k_init<<<(270912 + 255) / 256, 256, 0, stream>>>(st, 270912);
  k_setpsum<<<1, 64, 0, stream>>>(a.psum);
  k_prevmel<<<(TT * BB * MELD + 255) / 256, 256, 0, stream>>>(a);
  k_spkvec<<<(BB * 1024 + 255) / 256, 256, 0, stream>>>(a);
  k_spkq<<<(BB * 128 + 255) / 256, 256, 0, stream>>>(a);
  k_prep81<<<(81 * 1024 + 255) / 256, 256, 0, stream>>>(a);

  // prenet1 -> X (temp), prenet2 -> p
  k_gemm<<<dim3(16, 32), 256, 0, stream>>>(a.prevmel, a.Wpre1, a.bpre1, a.X, 4096, 1024, 80, 1);
  k_gemm<<<dim3(16, 32), 256, 0, stream>>>(a.X, a.Wpre2, a.bpre2, a.p, 4096, 1024, 1024, 1);
  // qp2 = p @ Wq^T (+ spk @ Wq^T)
  k_gemm<<<dim3(2, 32), 256, 0, stream>>>(a.p, a.Wq, nullptr, a.qp2, 4096, 128, 1024, 0);
  k_addspkq<<<(TT * BB * 128 + 255) / 256, 256, 0, stream>>>(a);
  // proc_mem = enc @ Wm^T -> X temp -> transpose to [b][att][l]
  k_gemm<<<dim3(2, 32), 256, 0, stream>>>(a.enc, a.Wm, nullptr, a.X, 4096, 128, 256, 0);
  k_pm_transpose<<<(BB * 128 * LL + 255) / 256, 256, 0, stream>>>(a);

  // barrier-cost probe (512 empty barriers) — rocprof-visible as its own dispatch
  {
    void* kargs[] = {(void*)&a};
    hipError_t e = hipLaunchCooperativeKernel(reinterpret_cast<const void*>(&k_barprobe),
                                              dim3(256), dim3(256), kargs, 0, stream);
    if (e != hipSuccess) k_barprobe<<<256, 256, 0, stream>>>(a);
  }

  // persistent decoder: 256 WGs (1/CU), cooperative; fallback to plain launch
  {
    void* kargs[] = {(void*)&a};
    hipError_t e = hipLaunchCooperativeKernel(reinterpret_cast<const void*>(&k_persist),
                                              dim3(256), dim3(256), kargs, 0, stream);
    if (e != hipSuccess) k_persist<<<256, 256, 0, stream>>>(a);
  }

  // mel/stop projection: h2_all @ W81^T -> tmp, then scatter
  k_gemm<<<dim3(2, 32), 256, 0, stream>>>(a.X, a.W81, a.b81, a.tmp, 4096, 128, 1024, 0);
  k_finish<<<(4096 * 128 + 255) / 256, 256, 0, stream>>>(a);
}

// Round 7
// 14026.767 us; speedup vs baseline: 1.4616x; 1.2539x over previous
//
#include <hip/hip_runtime.h>

// Tacotron-2 style decoder, B=16, T=256, DEC=1024, ENC=256, MEL=80, ATT=128.
// R7: persistent weight-stationary kernel; BATCHED explicit-coherence (sc0 sc1).
//  - R6 diagnosis: __hip_atomic_* loads are compiler-serialized (load; waitcnt;
//    use) -> ~100 L3 round-trips/WG/iter at ~800cyc each = ~50us of the 63us iter.
//  - Fix: inline-asm global_load/store with sc0 sc1 (L2-bypass, L3 = coherence
//    point), batched 8 loads per s_waitcnt vmcnt(0). Same bytes, same values,
//    ~25x fewer serialized latencies. Barrier polls use the same asm loads
//    (also removes the stale-poll 44ms-outlier class).
//  - Structure/numerics identical to R6 (passed): pipeline
//    { attn(t) || R(t-1) || LSTM1(t-2) || LSTM2(t-3) }, 259 iters, 1 barrier/iter,
//    LSTM weights stationary in VGPRs, fp32 throughout.

namespace {

constexpr int TT = 256, BB = 16, LL = 256, MELD = 80, FILTD = 32, KC = 31;
constexpr int P1 = 2308;  // LSTM1 xs pitch (2304+4)
constexpr int P2 = 2052;  // LSTM2 xs pitch (2048+4)

typedef float f32x4 __attribute__((ext_vector_type(4)));

struct Args {
  const float *enc, *spe, *mels;
  const float *Wpre1, *bpre1, *Wpre2, *bpre2, *Wsp, *bsp;
  const float *Wq, *Wm, *Wconv, *Wloc, *vatt;
  const float *Wih1, *Whh1, *bih1, *bhh1;
  const float *Wih2, *Whh2, *bih2, *bhh2;
  const float *Wmel, *bmel, *Wstop, *bstop;
  float *p, *X, *qp2, *pm2, *prevmel;
  float *h1a, *h1b, *c1, *h2a, *h2b, *c2;
  float *cum, *wexp, *uctx, *pctx, *psum, *spkvec, *spkq;
  float *W81, *b81, *tmp;
  int *slots, *epoch, *pslots, *pepoch;  // padded: slot i at [i*32]
  float *out;
};

__device__ __forceinline__ float fast_tanh(float x) {
  float ax = fabsf(x);
  float e = __expf(-2.f * ax);
  float t = (1.f - e) / (1.f + e);
  return copysignf(t, x);
}
__device__ __forceinline__ float fast_sig(float x) { return 1.f / (1.f + __expf(-x)); }

// ---- explicit-coherence primitives: sc0 sc1 = bypass L1/L2, L3 is PoC ----
__device__ __forceinline__ float cld1(const float* p) {
  float v;
  asm volatile("global_load_dword %0, %1, off sc0 sc1\n\ts_waitcnt vmcnt(0)"
               : "=v"(v) : "v"(p) : "memory");
  return v;
}
__device__ __forceinline__ int cldi(const int* p) {
  int v;
  asm volatile("global_load_dword %0, %1, off sc0 sc1\n\ts_waitcnt vmcnt(0)"
               : "=v"(v) : "v"(p) : "memory");
  return v;
}
__device__ __forceinline__ void cst1(float* p, float v) {
  asm volatile("global_store_dword %0, %1, off sc0 sc1" :: "v"(p), "v"(v) : "memory");
}
__device__ __forceinline__ void csti(int* p, int v) {
  asm volatile("global_store_dword %0, %1, off sc0 sc1" :: "v"(p), "v"(v) : "memory");
}
// 4x float4 coherent loads, ONE waitcnt
__device__ __forceinline__ void cld4(f32x4 d[4], const f32x4* q0, const f32x4* q1,
                                     const f32x4* q2, const f32x4* q3) {
  asm volatile(
      "global_load_dwordx4 %0, %4, off sc0 sc1\n\t"
      "global_load_dwordx4 %1, %5, off sc0 sc1\n\t"
      "global_load_dwordx4 %2, %6, off sc0 sc1\n\t"
      "global_load_dwordx4 %3, %7, off sc0 sc1\n\t"
      "s_waitcnt vmcnt(0)"
      : "=&v"(d[0]), "=&v"(d[1]), "=&v"(d[2]), "=&v"(d[3])
      : "v"(q0), "v"(q1), "v"(q2), "v"(q3)
      : "memory");
}
// 8x float4 coherent loads, ONE waitcnt
__device__ __forceinline__ void cld8(f32x4 d[8], const f32x4* q0, const f32x4* q1,
                                     const f32x4* q2, const f32x4* q3, const f32x4* q4,
                                     const f32x4* q5, const f32x4* q6, const f32x4* q7) {
  asm volatile(
      "global_load_dwordx4 %0, %8, off sc0 sc1\n\t"
      "global_load_dwordx4 %1, %9, off sc0 sc1\n\t"
      "global_load_dwordx4 %2, %10, off sc0 sc1\n\t"
      "global_load_dwordx4 %3, %11, off sc0 sc1\n\t"
      "global_load_dwordx4 %4, %12, off sc0 sc1\n\t"
      "global_load_dwordx4 %5, %13, off sc0 sc1\n\t"
      "global_load_dwordx4 %6, %14, off sc0 sc1\n\t"
      "global_load_dwordx4 %7, %15, off sc0 sc1\n\t"
      "s_waitcnt vmcnt(0)"
      : "=&v"(d[0]), "=&v"(d[1]), "=&v"(d[2]), "=&v"(d[3]),
        "=&v"(d[4]), "=&v"(d[5]), "=&v"(d[6]), "=&v"(d[7])
      : "v"(q0), "v"(q1), "v"(q2), "v"(q3), "v"(q4), "v"(q5), "v"(q6), "v"(q7)
      : "memory");
}
// 8x dword coherent loads, ONE waitcnt
__device__ __forceinline__ void cld8d(float d[8], const float* q0, const float* q1,
                                      const float* q2, const float* q3, const float* q4,
                                      const float* q5, const float* q6, const float* q7) {
  asm volatile(
      "global_load_dword %0, %8, off sc0 sc1\n\t"
      "global_load_dword %1, %9, off sc0 sc1\n\t"
      "global_load_dword %2, %10, off sc0 sc1\n\t"
      "global_load_dword %3, %11, off sc0 sc1\n\t"
      "global_load_dword %4, %12, off sc0 sc1\n\t"
      "global_load_dword %5, %13, off sc0 sc1\n\t"
      "global_load_dword %6, %14, off sc0 sc1\n\t"
      "global_load_dword %7, %15, off sc0 sc1\n\t"
      "s_waitcnt vmcnt(0)"
      : "=&v"(d[0]), "=&v"(d[1]), "=&v"(d[2]), "=&v"(d[3]),
        "=&v"(d[4]), "=&v"(d[5]), "=&v"(d[6]), "=&v"(d[7])
      : "v"(q0), "v"(q1), "v"(q2), "v"(q3), "v"(q4), "v"(q5), "v"(q6), "v"(q7)
      : "memory");
}

// Fence-free tree barrier, explicit-coherence polls. target = iter+1 (monotone).
// __syncthreads() emits s_waitcnt vmcnt(0) -> this WG's sc0sc1 stores are at L3
// before tid0 signals.
__device__ __forceinline__ void gridbar(int* slots, int* epoch, int target) {
  __syncthreads();
  if (blockIdx.x == 0) {
    if (threadIdx.x == 0) csti(&slots[0], target);
    while (cldi(&slots[threadIdx.x * 32]) < target) __builtin_amdgcn_s_sleep(1);
    __syncthreads();
    if (threadIdx.x == 0) csti(epoch, target);
  } else {
    if (threadIdx.x == 0) {
      csti(&slots[blockIdx.x * 32], target);
      while (cldi(epoch) < target) __builtin_amdgcn_s_sleep(8);
    }
  }
  __syncthreads();
}

__global__ void k_init(float* base, int n) {
  int i = blockIdx.x * blockDim.x + threadIdx.x;
  if (i < n) base[i] = 0.f;
}

// psum[1][b][0] = 1.0 : divisor for the zeroed step-(-1) attention weights
__global__ void k_setpsum(float* psum) {
  if (threadIdx.x < 16) psum[256 + threadIdx.x * 16] = 1.f;
}

__global__ void k_prevmel(Args a) {
  int i = blockIdx.x * blockDim.x + threadIdx.x;  // (t*16+b)*80+m
  if (i >= TT * BB * MELD) return;
  int m = i % MELD;
  int tb = i / MELD;
  int b = tb & 15, t = tb >> 4;
  a.prevmel[i] = (t == 0) ? 0.f : a.mels[(b * TT + t) * MELD + m];
}

__global__ void k_spkvec(Args a) {
  int i = blockIdx.x * blockDim.x + threadIdx.x;
  if (i >= BB * 1024) return;
  int b = i >> 10, j = i & 1023;
  const float* x = a.spe + b * 256;
  const float* w = a.Wsp + j * 256;
  float s = a.bsp[j];
  for (int k = 0; k < 256; ++k) s += x[k] * w[k];
  a.spkvec[i] = s;
}

__global__ void k_spkq(Args a) {
  int i = blockIdx.x * blockDim.x + threadIdx.x;
  if (i >= BB * 128) return;
  int b = i >> 7, q = i & 127;
  const float* x = a.spkvec + b * 1024;
  const float* w = a.Wq + q * 1024;
  float s = 0.f;
  for (int k = 0; k < 1024; ++k) s += x[k] * w[k];
  a.spkq[i] = s;
}

__global__ void k_prep81(Args a) {
  int i = blockIdx.x * blockDim.x + threadIdx.x;
  if (i < 81 * 1024) {
    int r = i >> 10, k = i & 1023;
    a.W81[i] = (r < 80) ? a.Wmel[r * 1024 + k] : a.Wstop[k];
  }
  if (i < 81) a.b81[i] = (i < 80) ? a.bmel[i] : a.bstop[0];
}

// C[M,N] = act(A[M,K] @ B[N,K]^T + bias[N]); 128x64 tile, 8x4 per thread.
__global__ __launch_bounds__(256) void k_gemm(const float* __restrict__ A,
                                              const float* __restrict__ Bm,
                                              const float* __restrict__ bias,
                                              float* __restrict__ C,
                                              int M, int N, int K, int act) {
  __shared__ __align__(16) float As[16][132];
  __shared__ __align__(16) float Bs[16][68];
  const int bm = blockIdx.y * 128, bn = blockIdx.x * 64;
  const int tid = threadIdx.x;
  const int tm = (tid >> 4) * 8, tn = (tid & 15) * 4;
  float acc[8][4] = {};
  for (int k0 = 0; k0 < K; k0 += 16) {
    for (int i = tid; i < 512; i += 256) {
      int m = i >> 2, kq = i & 3;
      float4 v = *(const float4*)(A + (size_t)(bm + m) * K + k0 + kq * 4);
      As[kq * 4 + 0][m] = v.x; As[kq * 4 + 1][m] = v.y;
      As[kq * 4 + 2][m] = v.z; As[kq * 4 + 3][m] = v.w;
    }
    {
      int m = tid >> 2, kq = tid & 3;
      float4 v = *(const float4*)(Bm + (size_t)(bn + m) * K + k0 + kq * 4);
      Bs[kq * 4 + 0][m] = v.x; Bs[kq * 4 + 1][m] = v.y;
      Bs[kq * 4 + 2][m] = v.z; Bs[kq * 4 + 3][m] = v.w;
    }
    __syncthreads();
#pragma unroll
    for (int kk = 0; kk < 16; ++kk) {
      float4 a0 = *(const float4*)&As[kk][tm];
      float4 a1 = *(const float4*)&As[kk][tm + 4];
      float4 b0 = *(const float4*)&Bs[kk][tn];
      float av[8] = {a0.x, a0.y, a0.z, a0.w, a1.x, a1.y, a1.z, a1.w};
      float bv[4] = {b0.x, b0.y, b0.z, b0.w};
#pragma unroll
      for (int i = 0; i < 8; ++i)
#pragma unroll
        for (int j = 0; j < 4; ++j) acc[i][j] += av[i] * bv[j];
    }
    __syncthreads();
  }
#pragma unroll
  for (int i = 0; i < 8; ++i)
#pragma unroll
    for (int j = 0; j < 4; ++j) {
      float v = acc[i][j];
      if (bias) v += bias[bn + tn + j];
      if (act == 1) v = fmaxf(v, 0.f);
      C[(size_t)(bm + tm + i) * N + bn + tn + j] = v;
    }
}

__global__ void k_pm_transpose(Args a) {
  int i = blockIdx.x * blockDim.x + threadIdx.x;  // dest (b*128+q)*256 + l
  if (i >= BB * 128 * LL) return;
  int l = i & 255;
  int rest = i >> 8;
  int q = rest & 127, b = rest >> 7;
  a.pm2[i] = a.X[(size_t)((b << 8) + l) * 128 + q];
}

__global__ void k_addspkq(Args a) {
  int i = blockIdx.x * blockDim.x + threadIdx.x;
  if (i >= TT * BB * 128) return;
  int q = i & 127, b = (i >> 7) & 15;
  a.qp2[i] += a.spkq[b * 128 + q];
}

// barrier-cost probe: 512 empty grid barriers
__global__ __launch_bounds__(256, 1) void k_barprobe(Args a) {
  for (int t = 0; t < 512; ++t) gridbar(a.pslots, a.pepoch, t + 1);
}

// ================= persistent decoder loop =================
// iter t: attn(t) || R(t-1) || LSTM1(t-2) || LSTM2(t-3); 259 iterations.
__global__ __launch_bounds__(256, 1) void k_persist(Args a) {
  __shared__ __align__(16) float xs[16 * P1];  // union: attn scratch / x / reduce
  __shared__ float gbuf[16][20];
  const int wg = blockIdx.x, tid = threadIdx.x;
  const int wv = tid >> 6, lane = tid & 63;
  const int d0 = wg * 4, kl = lane * 4;

  // ---- stationary weights (loaded once, plain cached) ----
  float4 wL1[9][4];
  float4 wL2[8][4];
#pragma unroll
  for (int q = 0; q < 4; ++q) {
    const int row = wv * 1024 + d0 + q;
    const float* rih1 = a.Wih1 + (size_t)row * 1280;
    const float* rhh1 = a.Whh1 + (size_t)row * 1024;
    const float* rih2 = a.Wih2 + (size_t)row * 1024;
    const float* rhh2 = a.Whh2 + (size_t)row * 1024;
#pragma unroll
    for (int kb = 0; kb < 9; ++kb)
      wL1[kb][q] = (kb < 5) ? *(const float4*)(rih1 + kb * 256 + kl)
                            : *(const float4*)(rhh1 + kb * 256 + kl - 1280);
#pragma unroll
    for (int kb = 0; kb < 8; ++kb)
      wL2[kb][q] = (kb < 4) ? *(const float4*)(rih2 + kb * 256 + kl)
                            : *(const float4*)(rhh2 + kb * 256 + kl - 1024);
  }
  const int row_r = wv * 1024 + d0 + (lane >> 4);
  const float bsum1 = a.bih1[row_r] + a.bhh1[row_r];
  const float bsum2 = a.bih2[row_r] + a.bhh2[row_r];

  for (int t = 0; t < 259; ++t) {
    const int cur = t & 1, prv = cur ^ 1;

    // ---------- attention(t) ----------
    if (t < 256) {
      float* loc0 = xs;
      float* loc1 = xs + 64;
      float* F = xs + 128;     // 32 x 17
      float* expv = xs + 672;  // 16
      const int b = wg >> 4, c = wg & 15, l0 = c << 4;
      // softmax divisor of step t-1: 16 contiguous psum floats, one 4-wide batch
      float sm;
      {
        const f32x4* ps4 = (const f32x4*)(a.psum + prv * 256 + b * 16);
        f32x4 pd[4];
        cld4(pd, ps4, ps4 + 1, ps4 + 2, ps4 + 3);
        sm = 0.f;
#pragma unroll
        for (int i = 0; i < 4; ++i) sm += pd[i][0] + pd[i][1] + pd[i][2] + pd[i][3];
      }
      const float inv_ps = 1.f / sm;
      if (tid < 64) {
        int lp = l0 - 16 + tid;
        bool ok = (lp >= 0 && lp < LL);
        float we = 0.f, cm = 0.f;
        if (ok) {
          we = cld1(a.wexp + prv * 4096 + b * 256 + lp) * inv_ps;
          cm = cld1(a.cum + prv * 4096 + b * 256 + lp);
        }
        loc0[tid] = we;
        loc1[tid] = ok ? (cm + we) : 0.f;
      }
      __syncthreads();
      // cum(t) own slice = cumulative through step t-1
      if (tid < 16) cst1(a.cum + cur * 4096 + b * 256 + l0 + tid, loc1[16 + tid]);
      for (int idx = tid; idx < FILTD * 16; idx += 256) {
        int fc = idx >> 4, ll = idx & 15;
        const float* w = a.Wconv + fc * 62;
        float s = 0.f;
#pragma unroll
        for (int k = 0; k < KC; ++k) {
          s += w[k] * loc0[ll + k + 1];
          s += w[31 + k] * loc1[ll + k + 1];
        }
        F[fc * 17 + ll] = s;
      }
      __syncthreads();
      {
        const int ll = tid >> 4, ag = tid & 15;
        const int l = l0 + ll;
        const float* qpb = a.qp2 + (size_t)((t << 4) + b) * 128;
        const float* pmb = a.pm2 + (size_t)b * 128 * 256;
        float s = 0.f;
        for (int q = ag * 8; q < ag * 8 + 8; ++q) {
          float x = qpb[q] + pmb[q * 256 + l];
          const float* wl = a.Wloc + q * 32;
#pragma unroll
          for (int fc = 0; fc < FILTD; ++fc) x += wl[fc] * F[fc * 17 + ll];
          s += a.vatt[q] * fast_tanh(x);
        }
        s += __shfl_down(s, 8, 16);
        s += __shfl_down(s, 4, 16);
        s += __shfl_down(s, 2, 16);
        s += __shfl_down(s, 1, 16);
        if (ag == 0) {
          float ex = __expf(s);  // |e| small -> no max-subtraction needed
          expv[ll] = ex;
          cst1(a.wexp + cur * 4096 + b * 256 + l, ex);
        }
      }
      __syncthreads();
      if (tid == 0) {
        float s = 0.f;
#pragma unroll
        for (int i = 0; i < 16; ++i) s += expv[i];
        cst1(a.psum + cur * 256 + b * 16 + c, s);
      }
      {
        float s = 0.f;
        const float* eb = a.enc + (size_t)((b << 8) + l0) * 256 + tid;
#pragma unroll
        for (int ll = 0; ll < 16; ++ll) s += expv[ll] * eb[ll * 256];
        cst1(a.pctx + cur * 65536 + (b * 16 + c) * 256 + tid, s);
      }
      __syncthreads();  // xs free
    }

    // ---------- R(s = t-1): reduce pctx -> normalized uctx ----------
    if (wg < 16 && t >= 1 && t <= 256) {
      const int s = t - 1, par = s & 1, b = wg;
      float sm;
      {
        const f32x4* ps4 = (const f32x4*)(a.psum + par * 256 + b * 16);
        f32x4 pd[4];
        cld4(pd, ps4, ps4 + 1, ps4 + 2, ps4 + 3);
        sm = 0.f;
#pragma unroll
        for (int i = 0; i < 4; ++i) sm += pd[i][0] + pd[i][1] + pd[i][2] + pd[i][3];
      }
      const float inv = 1.f / sm;
      const float* pc = a.pctx + par * 65536 + b * 4096 + tid;
      float d[8];
      float acc = 0.f;
      cld8d(d, pc, pc + 256, pc + 512, pc + 768, pc + 1024, pc + 1280, pc + 1536,
            pc + 1792);
#pragma unroll
      for (int i = 0; i < 8; ++i) acc += d[i];
      cld8d(d, pc + 2048, pc + 2304, pc + 2560, pc + 2816, pc + 3072, pc + 3328,
            pc + 3584, pc + 3840);
#pragma unroll
      for (int i = 0; i < 8; ++i) acc += d[i];
      cst1(a.uctx + par * 4096 + b * 256 + tid, acc * inv);
    }

    // ---------- LSTM1(s1 = t-2) ----------
    if (t >= 2 && t <= 257) {
      const int s1 = t - 2;
      const float* pt = a.p + (size_t)s1 * 16384;
      const float* h1r = (s1 & 1) ? a.h1a : a.h1b;  // h1(s1-1)
      float* h1w = (s1 & 1) ? a.h1b : a.h1a;        // h1(s1)
      // p: plain cached (read-only, L2-warm)
      for (int k = 0; k < 16; ++k) {
        int i4 = tid + k * 256, b = i4 >> 8, kq = i4 & 255;
        *(f32x4*)(xs + b * P1 + kq * 4) = *(const f32x4*)(pt + (size_t)i4 * 4);
      }
      // uctx: coherent, one 4-batch
      {
        const f32x4* q = (const f32x4*)(a.uctx + (size_t)(s1 & 1) * 4096);
        f32x4 d[4];
        cld4(d, q + tid, q + tid + 256, q + tid + 512, q + tid + 768);
#pragma unroll
        for (int k = 0; k < 4; ++k) {
          int i4 = tid + k * 256, b = i4 >> 6, kq = i4 & 63;
          *(f32x4*)(xs + b * P1 + 1024 + kq * 4) = d[k];
        }
      }
      // h1: coherent, two 8-batches
      {
        const f32x4* q = (const f32x4*)h1r;
        f32x4 d[8];
#pragma unroll
        for (int hb = 0; hb < 2; ++hb) {
          const f32x4* qq = q + tid + hb * 2048;
          cld8(d, qq, qq + 256, qq + 512, qq + 768, qq + 1024, qq + 1280, qq + 1536,
               qq + 1792);
#pragma unroll
          for (int k = 0; k < 8; ++k) {
            int i4 = tid + (hb * 8 + k) * 256, b = i4 >> 8, kq = i4 & 255;
            *(f32x4*)(xs + b * P1 + 1280 + kq * 4) = d[k];
          }
        }
      }
      __syncthreads();
      float acc[4][16];
#pragma unroll
      for (int q = 0; q < 4; ++q)
#pragma unroll
        for (int b = 0; b < 16; ++b) acc[q][b] = 0.f;
#pragma unroll
      for (int kb = 0; kb < 9; ++kb) {
        const float* xb = xs + kb * 256 + kl;
#pragma unroll
        for (int b = 0; b < 16; ++b) {
          float4 x4 = *(const float4*)(xb + b * P1);
#pragma unroll
          for (int q = 0; q < 4; ++q) {
            acc[q][b] += wL1[kb][q].x * x4.x;
            acc[q][b] += wL1[kb][q].y * x4.y;
            acc[q][b] += wL1[kb][q].z * x4.z;
            acc[q][b] += wL1[kb][q].w * x4.w;
          }
        }
      }
      __syncthreads();  // xs reads done -> reuse as reduce buffer
      float* red = xs + wv * 4352;
#pragma unroll
      for (int q = 0; q < 4; ++q)
#pragma unroll
        for (int b = 0; b < 16; ++b) red[(q * 16 + b) * 68 + lane] = acc[q][b];
      __syncthreads();
      {
        const float* rr = xs + wv * 4352 + lane * 68;
        float4 s4 = {0.f, 0.f, 0.f, 0.f};
#pragma unroll
        for (int i = 0; i < 16; ++i) {
          float4 v = *(const float4*)(rr + i * 4);
          s4.x += v.x; s4.y += v.y; s4.z += v.z; s4.w += v.w;
        }
        gbuf[wv * 4 + (lane >> 4)][lane & 15] = s4.x + s4.y + s4.z + s4.w + bsum1;
      }
      __syncthreads();
      if (tid < 64) {
        int dd = tid >> 4, b = tid & 15;
        int d = d0 + dd;
        float gi = gbuf[0 + dd][b], gf = gbuf[4 + dd][b];
        float gg = gbuf[8 + dd][b], go = gbuf[12 + dd][b];
        float co = a.c1[b * 1024 + d];        // private to this WG: plain cached
        float cn = fast_sig(gf) * co + fast_sig(gi) * fast_tanh(gg);
        float hn = fast_sig(go) * fast_tanh(cn);
        a.c1[b * 1024 + d] = cn;
        cst1(h1w + b * 1024 + d, hn);         // cross-WG: coherent
      }
      __syncthreads();
    }

    // ---------- LSTM2(s2 = t-3) ----------
    if (t >= 3) {
      const int s2 = t - 3;
      const float* h1s = (s2 & 1) ? a.h1b : a.h1a;  // h1(s2)
      const float* h2r = (s2 & 1) ? a.h2a : a.h2b;  // h2(s2-1)
      float* h2w = (s2 & 1) ? a.h2b : a.h2a;        // h2(s2)
      {
        f32x4 d[8];
        const f32x4* q1 = (const f32x4*)h1s;
        const f32x4* q2 = (const f32x4*)h2r;
#pragma unroll
        for (int hb = 0; hb < 2; ++hb) {
          const f32x4* qq = q1 + tid + hb * 2048;
          cld8(d, qq, qq + 256, qq + 512, qq + 768, qq + 1024, qq + 1280, qq + 1536,
               qq + 1792);
#pragma unroll
          for (int k = 0; k < 8; ++k) {
            int i4 = tid + (hb * 8 + k) * 256, b = i4 >> 8, kq = i4 & 255;
            *(f32x4*)(xs + b * P2 + kq * 4) = d[k];
          }
        }
#pragma unroll
        for (int hb = 0; hb < 2; ++hb) {
          const f32x4* qq = q2 + tid + hb * 2048;
          cld8(d, qq, qq + 256, qq + 512, qq + 768, qq + 1024, qq + 1280, qq + 1536,
               qq + 1792);
#pragma unroll
          for (int k = 0; k < 8; ++k) {
            int i4 = tid + (hb * 8 + k) * 256, b = i4 >> 8, kq = i4 & 255;
            *(f32x4*)(xs + b * P2 + 1024 + kq * 4) = d[k];
          }
        }
      }
      __syncthreads();
      float acc[4][16];
#pragma unroll
      for (int q = 0; q < 4; ++q)
#pragma unroll
        for (int b = 0; b < 16; ++b) acc[q][b] = 0.f;
#pragma unroll
      for (int kb = 0; kb < 8; ++kb) {
        const float* xb = xs + kb * 256 + kl;
#pragma unroll
        for (int b = 0; b < 16; ++b) {
          float4 x4 = *(const float4*)(xb + b * P2);
#pragma unroll
          for (int q = 0; q < 4; ++q) {
            acc[q][b] += wL2[kb][q].x * x4.x;
            acc[q][b] += wL2[kb][q].y * x4.y;
            acc[q][b] += wL2[kb][q].z * x4.z;
            acc[q][b] += wL2[kb][q].w * x4.w;
          }
        }
      }
      __syncthreads();
      float* red = xs + wv * 4352;
#pragma unroll
      for (int q = 0; q < 4; ++q)
#pragma unroll
        for (int b = 0; b < 16; ++b) red[(q * 16 + b) * 68 + lane] = acc[q][b];
      __syncthreads();
      {
        const float* rr = xs + wv * 4352 + lane * 68;
        float4 s4 = {0.f, 0.f, 0.f, 0.f};
#pragma unroll
        for (int i = 0; i < 16; ++i) {
          float4 v = *(const float4*)(rr + i * 4);
          s4.x += v.x; s4.y += v.y; s4.z += v.z; s4.w += v.w;
        }
        gbuf[wv * 4 + (lane >> 4)][lane & 15] = s4.x + s4.y + s4.z + s4.w + bsum2;
      }
      __syncthreads();
      if (tid < 64) {
        int dd = tid >> 4, b = tid & 15;
        int d = d0 + dd;
        float gi = gbuf[0 + dd][b], gf = gbuf[4 + dd][b];
        float gg = gbuf[8 + dd][b], go = gbuf[12 + dd][b];
        float co = a.c2[b * 1024 + d];        // private: plain cached
        float cn = fast_sig(gf) * co + fast_sig(gi) * fast_tanh(gg);
        float hn = fast_sig(go) * fast_tanh(cn);
        a.c2[b * 1024 + d] = cn;
        cst1(h2w + b * 1024 + d, hn);         // cross-WG: coherent
        a.X[(size_t)(s2 * 16 + b) * 1024 + d] = hn;  // epilogue-only: plain
      }
    }

    if (t < 258) gridbar(a.slots, a.epoch, t + 1);
  }
}

__global__ void k_finish(Args a) {
  int i = blockIdx.x * blockDim.x + threadIdx.x;  // tb*128+col
  if (i >= 4096 * 128) return;
  int col = i & 127, tb = i >> 7;
  int t = tb >> 4, b = tb & 15;
  float v = a.tmp[i];
  if (col < 80) a.out[(size_t)(b * 256 + t) * 80 + col] = v;
  else if (col == 80) a.out[327680 + b * 256 + t] = fast_sig(v);
}

}  // namespace

extern "C" void kernel_launch(void* const* d_in, const int* in_sizes, int n_in,
                              void* d_out, int out_size, void* d_ws, size_t ws_size,
                              hipStream_t stream) {
  float* ws = (float*)d_ws;
  Args a;
  a.enc = (const float*)d_in[0];
  a.spe = (const float*)d_in[1];
  a.mels = (const float*)d_in[2];
  a.Wpre1 = (const float*)d_in[3];  a.bpre1 = (const float*)d_in[4];
  a.Wpre2 = (const float*)d_in[5];  a.bpre2 = (const float*)d_in[6];
  a.Wsp = (const float*)d_in[7];    a.bsp = (const float*)d_in[8];
  a.Wq = (const float*)d_in[9];     a.Wm = (const float*)d_in[10];
  a.Wconv = (const float*)d_in[11]; a.Wloc = (const float*)d_in[12];
  a.vatt = (const float*)d_in[13];
  a.Wih1 = (const float*)d_in[14];  a.Whh1 = (const float*)d_in[15];
  a.bih1 = (const float*)d_in[16];  a.bhh1 = (const float*)d_in[17];
  a.Wih2 = (const float*)d_in[18];  a.Whh2 = (const float*)d_in[19];
  a.bih2 = (const float*)d_in[20];  a.bhh2 = (const float*)d_in[21];
  a.Wmel = (const float*)d_in[22];  a.bmel = (const float*)d_in[23];
  a.Wstop = (const float*)d_in[24]; a.bstop = (const float*)d_in[25];

  // ws layout (floats), total 10,382,016 floats ~= 41.5 MB
  a.p    = ws + 0;         // 4096x1024
  a.X    = ws + 4194304;   // prenet hidden -> pm temp -> h2_all
  a.qp2  = ws + 8388608;   // 4096x128
  a.pm2  = ws + 8912896;   // 16x128x256
  float* st = ws + 9437184;  // STATE block, 270,912 floats (zeroed each launch)
  a.h1a = st + 0;      a.h1b = st + 16384;
  a.c1  = st + 32768;
  a.h2a = st + 49152;  a.h2b = st + 65536;
  a.c2  = st + 81920;
  a.cum  = st + 98304;    // [2][16][256]
  a.wexp = st + 106496;   // [2][16][256]
  a.uctx = st + 114688;   // [2][16][256]
  a.pctx = st + 122880;   // [2][16][16][256]
  a.psum = st + 253952;   // [2][16][16]
  a.slots  = (int*)(st + 254464);  // 256 slots x 32-int pad
  a.epoch  = (int*)(st + 262656);  // 1 x 32-int pad
  a.pslots = (int*)(st + 262688);  // probe: 256 x 32
  a.pepoch = (int*)(st + 270880);  // probe: 1 x 32
  a.spkvec = ws + 9708096;  // 16x1024
  a.spkq   = ws + 9724480;  // 16x128
  a.W81    = ws + 9726528;  // 128x1024 (rows 81..127 unused)
  a.b81    = ws + 9857600;  // 128
  a.tmp    = ws + 9857728;  // 4096x128
  a.prevmel = a.tmp;        // prologue-only, aliases epilogue tmp
  a.out = (float*)d_out;

  k_init<<<(270912 + 255) / 256, 256, 0, stream>>>(st, 270912);
  k_setpsum<<<1, 64, 0, stream>>>(a.psum);
  k_prevmel<<<(TT * BB * MELD + 255) / 256, 256, 0, stream>>>(a);
  k_spkvec<<<(BB * 1024 + 255) / 256, 256, 0, stream>>>(a);
  k_spkq<<<(BB * 128 + 255) / 256, 256, 0, stream>>>(a);
  k_prep81<<<(81 * 1024 + 255) / 256, 256, 0, stream>>>(a);

  // prenet1 -> X (temp), prenet2 -> p
  k_gemm<<<dim3(16, 32), 256, 0, stream>>>(a.prevmel, a.Wpre1, a.bpre1, a.X, 4096, 1024, 80, 1);
  k_gemm<<<dim3(16, 32), 256, 0, stream>>>(a.X, a.Wpre2, a.bpre2, a.p, 4096, 1024, 1024, 1);
  // qp2 = p @ Wq^T (+ spk @ Wq^T)
  k_gemm<<<dim3(2, 32), 256, 0, stream>>>(a.p, a.Wq, nullptr, a.qp2, 4096, 128, 1024, 0);
  k_addspkq<<<(TT * BB * 128 + 255) / 256, 256, 0, stream>>>(a);
  // proc_mem = enc @ Wm^T -> X temp -> transpose to [b][att][l]
  k_gemm<<<dim3(2, 32), 256, 0, stream>>>(a.enc, a.Wm, nullptr, a.X, 4096, 128, 256, 0);
  k_pm_transpose<<<(BB * 128 * LL + 255) / 256, 256, 0, stream>>>(a);

  // barrier-cost probe (512 empty barriers)
  {
    void* kargs[] = {(void*)&a};
    hipError_t e = hipLaunchCooperativeKernel(reinterpret_cast<const void*>(&k_barprobe),
                                              dim3(256), dim3(256), kargs, 0, stream);
    if (e != hipSuccess) k_barprobe<<<256, 256, 0, stream>>>(a);
  }

  // persistent decoder: 256 WGs (1/CU), cooperative; fallback to plain launch
  {
    void* kargs[] = {(void*)&a};
    hipError_t e = hipLaunchCooperativeKernel(reinterpret_cast<const void*>(&k_persist),
                                              dim3(256), dim3(256), kargs, 0, stream);
    if (e != hipSuccess) k_persist<<<256, 256, 0, stream>>>(a);
  }

  // mel/stop projection: h2_all @ W81^T -> tmp, then scatter
  k_gemm<<<dim3(2, 32), 256, 0, stream>>>(a.X, a.W81, a.b81, a.tmp, 4096, 128, 1024, 0);
  k_finish<<<(4096 * 128 + 255) / 256, 256, 0, stream>>>(a);
}